// Round 1
// baseline (795.942 us; speedup 1.0000x reference)
//
#include <hip/hip_runtime.h>
#include <math.h>

// Problem constants: B=2, H=16, S=2048, DK=64
#define S_LEN 2048
#define D_K   64
#define N_BH  32   // B*H

// ---------------------------------------------------------------------------
// Staging helper: load a 64x64 fp32 tile (row-major [r][d]) from global and
// store TRANSPOSED into LDS as [d][col'] with col' = r ^ (4*(d>>2)).
// The XOR swizzle makes the scatter stores bank-conflict-free (verified by
// hand: banks = (r0..) ^ 4*slot covers all 32 banks 2x per store instr).
// Readers must index col' = x ^ (4*(d>>2)) — with x a multiple of 4 this
// stays float4-contiguous and 16B-aligned.
// ---------------------------------------------------------------------------
__device__ __forceinline__ void stage_T64(const float* __restrict__ src,
                                          float* __restrict__ dst,
                                          float scale, int tid) {
  const int slot = tid & 15;   // float4 column slot within a source row
  const int r0   = tid >> 4;   // 0..15
#pragma unroll
  for (int p = 0; p < 4; ++p) {
    const int row = p * 16 + r0;
    const float4 v = *(const float4*)(src + row * 64 + slot * 4);
    const int col = row ^ (slot * 4);   // f(d) = 4*(d>>2) = 4*slot
    dst[(slot * 4 + 0) * 64 + col] = v.x * scale;
    dst[(slot * 4 + 1) * 64 + col] = v.y * scale;
    dst[(slot * 4 + 2) * 64 + col] = v.z * scale;
    dst[(slot * 4 + 3) * 64 + col] = v.w * scale;
  }
}

// Natural-layout staging (for V): [r][d], float4 stores, stride 64.
__device__ __forceinline__ void stage_N64(const float* __restrict__ src,
                                          float* __restrict__ dst, int tid) {
  const int slot = tid & 15;
  const int r0   = tid >> 4;
#pragma unroll
  for (int p = 0; p < 4; ++p) {
    const int row = p * 16 + r0;
    float4 v = *(const float4*)(src + row * 64 + slot * 4);
    *(float4*)(dst + row * 64 + slot * 4) = v;
  }
}

// 64x64 score tile accumulate: acc[i][j] += sum_d qT[d][4ty+i]*kT[d][4tx+j]
__device__ __forceinline__ void dot_tile(const float* __restrict__ qT,
                                         const float* __restrict__ kT,
                                         int ty, int tx, float acc[4][4]) {
#pragma unroll 4
  for (int d4 = 0; d4 < 16; ++d4) {
    const float* qp = qT + (d4 * 4) * 64 + 4 * (ty ^ d4);
    const float* kp = kT + (d4 * 4) * 64 + 4 * (tx ^ d4);
#pragma unroll
    for (int dd = 0; dd < 4; ++dd) {
      float4 qv = *(const float4*)(qp + dd * 64);
      float4 kv = *(const float4*)(kp + dd * 64);
      float a[4] = {qv.x, qv.y, qv.z, qv.w};
      float b[4] = {kv.x, kv.y, kv.z, kv.w};
#pragma unroll
      for (int i = 0; i < 4; ++i)
#pragma unroll
        for (int j = 0; j < 4; ++j)
          acc[i][j] = fmaf(a[i], b[j], acc[i][j]);
    }
  }
}

// ---------------------------------------------------------------------------
// Pass 1: per-(bh) column stats over the QUERY axis.
//   m[k] = max_q s[q,k],  l[k] = sum_q exp(s[q,k]-m[k]),  store m and 1/l.
// Block: (kc chunk of 64 key columns) x (bh). Streams all q in 64-row tiles.
// ---------------------------------------------------------------------------
__global__ __launch_bounds__(256) void colstats_kernel(
    const float* __restrict__ Q, const float* __restrict__ K,
    const int* __restrict__ mask,
    float* __restrict__ m_out, float* __restrict__ il_out) {
  __shared__ __align__(16) float kT[64 * 64];
  __shared__ __align__(16) float qT[64 * 64];
  __shared__ float red_m[64 * 17];
  __shared__ float red_l[64 * 17];

  const int tid = threadIdx.x;
  const int kc  = blockIdx.x;       // key-column chunk
  const int bh  = blockIdx.y;

  const float* Kbase = K + ((size_t)bh * S_LEN + (size_t)kc * 64) * D_K;
  const float* Qbase = Q + (size_t)bh * S_LEN * D_K;

  // K chunk staged once, scaled by 1/sqrt(64) so acc == score directly.
  stage_T64(Kbase, kT, 0.125f, tid);

  const int tx = tid & 15, ty = tid >> 4;
  float m_r[4], l_r[4];
#pragma unroll
  for (int j = 0; j < 4; ++j) { m_r[j] = -INFINITY; l_r[j] = 0.f; }

  const int kbase = kc * 64;

  for (int qc = 0; qc < S_LEN / 64; ++qc) {
    __syncthreads();                       // prior readers of qT done
    stage_T64(Qbase + (size_t)qc * 64 * D_K, qT, 1.0f, tid);
    __syncthreads();                       // qT (and 1st-iter kT) visible

    float acc[4][4] = {{0.f}};
    dot_tile(qT, kT, ty, tx, acc);

    // mask + online column-stat update (this thread owns q rows 4ty+i of
    // this chunk, key cols kbase+4tx+j across the whole kernel)
    int mk[16];
#pragma unroll
    for (int i = 0; i < 4; ++i) {
      int4 m4 = *(const int4*)(mask + (size_t)(qc * 64 + ty * 4 + i) * S_LEN
                               + kbase + tx * 4);
      mk[i * 4 + 0] = m4.x; mk[i * 4 + 1] = m4.y;
      mk[i * 4 + 2] = m4.z; mk[i * 4 + 3] = m4.w;
    }
#pragma unroll
    for (int j = 0; j < 4; ++j) {
      float s0 = mk[0 * 4 + j] ? -1e9f : acc[0][j];
      float s1 = mk[1 * 4 + j] ? -1e9f : acc[1][j];
      float s2 = mk[2 * 4 + j] ? -1e9f : acc[2][j];
      float s3 = mk[3 * 4 + j] ? -1e9f : acc[3][j];
      float mm = fmaxf(fmaxf(s0, s1), fmaxf(s2, s3));
      float nm = fmaxf(m_r[j], mm);
      l_r[j] = l_r[j] * __expf(m_r[j] - nm)
             + __expf(s0 - nm) + __expf(s1 - nm)
             + __expf(s2 - nm) + __expf(s3 - nm);
      m_r[j] = nm;
    }
  }

  // combine the 16 per-ty partials for each of the 64 columns
  __syncthreads();
#pragma unroll
  for (int j = 0; j < 4; ++j) {
    red_m[(tx * 4 + j) * 17 + ty] = m_r[j];
    red_l[(tx * 4 + j) * 17 + ty] = l_r[j];
  }
  __syncthreads();
  if (tid < 64) {
    float M = -INFINITY;
#pragma unroll
    for (int p = 0; p < 16; ++p) M = fmaxf(M, red_m[tid * 17 + p]);
    float L = 0.f;
#pragma unroll
    for (int p = 0; p < 16; ++p)
      L += red_l[tid * 17 + p] * __expf(red_m[tid * 17 + p] - M);
    m_out[(size_t)bh * S_LEN + kbase + tid]  = M;
    il_out[(size_t)bh * S_LEN + kbase + tid] = 1.0f / L;
  }
}

// ---------------------------------------------------------------------------
// Pass 2: out[q,d] = sum_k exp(s[q,k]-m[k])*il[k] * v[k,d]
// Block: (qc chunk of 64 query rows) x (bh). Streams all k in 64-col tiles.
// LDS exactly 64KB: qT + kT + pT + vS.
// ---------------------------------------------------------------------------
__global__ __launch_bounds__(256) void attn_out_kernel(
    const float* __restrict__ Q, const float* __restrict__ K,
    const float* __restrict__ V, const int* __restrict__ mask,
    const float* __restrict__ m_in, const float* __restrict__ il_in,
    float* __restrict__ out) {
  __shared__ __align__(16) float qT[64 * 64];
  __shared__ __align__(16) float kT[64 * 64];
  __shared__ __align__(16) float pT[64 * 64];   // p transposed: [k][q]
  __shared__ __align__(16) float vS[64 * 64];   // natural: [k][d]

  const int tid = threadIdx.x;
  const int qc  = blockIdx.x;
  const int bh  = blockIdx.y;

  const float* Qbase = Q + ((size_t)bh * S_LEN + (size_t)qc * 64) * D_K;
  const float* Kbase = K + (size_t)bh * S_LEN * D_K;
  const float* Vbase = V + (size_t)bh * S_LEN * D_K;

  // Q chunk staged once, carries the 1/8 scale.
  stage_T64(Qbase, qT, 0.125f, tid);

  const int tx = tid & 15, ty = tid >> 4;
  float oacc[4][4] = {{0.f}};

  for (int kc = 0; kc < S_LEN / 64; ++kc) {
    __syncthreads();   // prior phase readers of kT/vS/pT done
    stage_T64(Kbase + (size_t)kc * 64 * D_K, kT, 1.0f, tid);
    stage_N64(Vbase + (size_t)kc * 64 * D_K, vS, tid);
    __syncthreads();

    // scores for (q = 4ty+i, k = 4tx+j)
    float sacc[4][4] = {{0.f}};
    dot_tile(qT, kT, ty, tx, sacc);

    // column stats for this k chunk (thread's 4 columns are contiguous)
    float4 mv = *(const float4*)(m_in  + (size_t)bh * S_LEN + kc * 64 + tx * 4);
    float4 iv = *(const float4*)(il_in + (size_t)bh * S_LEN + kc * 64 + tx * 4);
    float mvj[4] = {mv.x, mv.y, mv.z, mv.w};
    float ivj[4] = {iv.x, iv.y, iv.z, iv.w};

    int mk[16];
#pragma unroll
    for (int i = 0; i < 4; ++i) {
      int4 m4 = *(const int4*)(mask + (size_t)(qc * 64 + ty * 4 + i) * S_LEN
                               + kc * 64 + tx * 4);
      mk[i * 4 + 0] = m4.x; mk[i * 4 + 1] = m4.y;
      mk[i * 4 + 2] = m4.z; mk[i * 4 + 3] = m4.w;
    }

    // p = exp(s - m[k]) * (1/l[k]); store transposed pT[k][q] as float4 over q
#pragma unroll
    for (int j = 0; j < 4; ++j) {
      float4 pv;
      pv.x = __expf((mk[0 * 4 + j] ? -1e9f : sacc[0][j]) - mvj[j]) * ivj[j];
      pv.y = __expf((mk[1 * 4 + j] ? -1e9f : sacc[1][j]) - mvj[j]) * ivj[j];
      pv.z = __expf((mk[2 * 4 + j] ? -1e9f : sacc[2][j]) - mvj[j]) * ivj[j];
      pv.w = __expf((mk[3 * 4 + j] ? -1e9f : sacc[3][j]) - mvj[j]) * ivj[j];
      *(float4*)(pT + (tx * 4 + j) * 64 + ty * 4) = pv;
    }
    __syncthreads();

    // out[q][d] += sum_kk p[q][kk] * v[kk][d]
#pragma unroll 8
    for (int kk = 0; kk < 64; ++kk) {
      float4 p4 = *(const float4*)(pT + kk * 64 + ty * 4);
      float4 v4 = *(const float4*)(vS + kk * 64 + tx * 4);
      float a[4] = {p4.x, p4.y, p4.z, p4.w};
      float b[4] = {v4.x, v4.y, v4.z, v4.w};
#pragma unroll
      for (int i = 0; i < 4; ++i)
#pragma unroll
        for (int j = 0; j < 4; ++j)
          oacc[i][j] = fmaf(a[i], b[j], oacc[i][j]);
    }
  }

  // write 64x64 output tile, float4 per (q row, d slot)
#pragma unroll
  for (int i = 0; i < 4; ++i) {
    float4 o = {oacc[i][0], oacc[i][1], oacc[i][2], oacc[i][3]};
    *(float4*)(out + ((size_t)bh * S_LEN + qc * 64 + ty * 4 + i) * D_K + tx * 4) = o;
  }
}

extern "C" void kernel_launch(void* const* d_in, const int* in_sizes, int n_in,
                              void* d_out, int out_size, void* d_ws, size_t ws_size,
                              hipStream_t stream) {
  (void)in_sizes; (void)n_in; (void)out_size; (void)ws_size;
  const float* q = (const float*)d_in[0];
  const float* k = (const float*)d_in[1];
  const float* v = (const float*)d_in[2];
  const int* mask = (const int*)d_in[3];
  float* out = (float*)d_out;

  // workspace: m[N_BH*S], inv_l[N_BH*S]  (512 KB total)
  float* mw  = (float*)d_ws;
  float* ilw = mw + (size_t)N_BH * S_LEN;

  dim3 grid(S_LEN / 64, N_BH);
  colstats_kernel<<<grid, 256, 0, stream>>>(q, k, mask, mw, ilw);
  attn_out_kernel<<<grid, 256, 0, stream>>>(q, k, v, mask, mw, ilw, out);
}

// Round 2
// 426.696 us; speedup vs baseline: 1.8654x; 1.8654x over previous
//
#include <hip/hip_runtime.h>
#include <math.h>

// B=2, H=16, S=2048, DK=64
#define S_LEN 2048
#define NCH   32          // S/64 chunks
#define N_BH  32

typedef short bf16x8 __attribute__((ext_vector_type(8)));
typedef float f32x4  __attribute__((ext_vector_type(4)));
typedef unsigned short u16;

#define MFMA(a,b,c) __builtin_amdgcn_mfma_f32_16x16x32_bf16((a),(b),(c),0,0,0)

// (1/sqrt(64)) * log2(e) folded into Q so scores are in log2 units and
// exp2f is a single v_exp_f32. Masked score = -1e9 (log2 units) in BOTH
// passes -> all-masked column degrades to exp2(0)=1 per row -> uniform.
#define SC     0.18033688011112042f
#define MASKED (-1.0e9f)
#define NEGBIG (-3.0e38f)

__device__ __forceinline__ u16 f2bf_rne(float x) {
  unsigned u = __float_as_uint(x);
  return (u16)((u + 0x7FFF + ((u >> 16) & 1)) >> 16);
}
// hi = bit-truncation, lo = RNE of residual; combined repr error ~2^-17
__device__ __forceinline__ void bfsplit(float x, u16& h, u16& l) {
  unsigned u = __float_as_uint(x);
  h = (u16)(u >> 16);
  float hf = __uint_as_float(u & 0xFFFF0000u);
  l = f2bf_rne(x - hf);
}

// ---------------------------------------------------------------------------
// Pass 1: column stats over the QUERY axis (softmax dim=2).
// Block = (kc 64 key-cols, bh); wave w owns cols 16w..16w+16 with K B-frags
// held in registers; streams q in 64-row tiles (Q split-staged in LDS).
// ---------------------------------------------------------------------------
__global__ __launch_bounds__(256) void pass1_colstats(
    const float* __restrict__ Q, const float* __restrict__ K,
    const int* __restrict__ mask,
    float* __restrict__ m2_out, float* __restrict__ il_out) {
  __shared__ u16 qh_s[4096];
  __shared__ u16 ql_s[4096];
  __shared__ int mk_s[4096];

  const int tid = threadIdx.x;
  const int lane = tid & 63;
  const int w = tid >> 6;
  const int c = lane & 15;
  const int g = lane >> 4;
  const int kc = blockIdx.x;
  const int bh = blockIdx.y;

  const float* Qb = Q + (size_t)bh * S_LEN * 64;
  const float* Kb = K + (size_t)bh * S_LEN * 64;

  // K B-frags for this wave's 16 columns, hi/lo, both d-halves (regs).
  bf16x8 kbh[2], kbl[2];
  {
    const int krow = kc * 64 + w * 16 + c;
#pragma unroll
    for (int h = 0; h < 2; ++h) {
      const float* src = Kb + (size_t)krow * 64 + h * 32 + g * 8;
      float4 x = *(const float4*)(src);
      float4 y = *(const float4*)(src + 4);
      float xs[8] = {x.x, x.y, x.z, x.w, y.x, y.y, y.z, y.w};
#pragma unroll
      for (int e = 0; e < 8; ++e) {
        u16 hh, ll; bfsplit(xs[e], hh, ll);
        kbh[h][e] = (short)hh; kbl[h][e] = (short)ll;
      }
    }
  }

  float m_r = NEGBIG, l_r = 0.f;
  const int slot = tid & 15, r0 = tid >> 4;

  for (int qc = 0; qc < NCH; ++qc) {
    __syncthreads();
    // stage Q (scaled + split) and mask tile, swizzled
#pragma unroll
    for (int p = 0; p < 4; ++p) {
      const int row = p * 16 + r0;
      float4 qv = *(const float4*)(Qb + (size_t)(qc * 64 + row) * 64 + slot * 4);
      float xs[4] = {qv.x, qv.y, qv.z, qv.w};
      u16 ha[4], la[4];
#pragma unroll
      for (int e = 0; e < 4; ++e) bfsplit(xs[e] * SC, ha[e], la[e]);
      const int idx = row * 64 + ((slot * 4) ^ ((row & 7) << 3));
      *(ushort4*)(qh_s + idx) = make_ushort4(ha[0], ha[1], ha[2], ha[3]);
      *(ushort4*)(ql_s + idx) = make_ushort4(la[0], la[1], la[2], la[3]);
      int4 mv = *(const int4*)(mask + (size_t)(qc * 64 + row) * S_LEN + kc * 64 + slot * 4);
      const int midx = row * 64 + ((slot * 4) ^ (((row >> 2) & 3) << 4));
      *(int4*)(mk_s + midx) = mv;
    }
    __syncthreads();

    const int colT = w * 16 + c;
#pragma unroll
    for (int qt = 0; qt < 4; ++qt) {
      const int arow = qt * 16 + c;
      const int abase = arow * 64, sw = (arow & 7) << 3;
      bf16x8 aqh[2], aql[2];
#pragma unroll
      for (int h = 0; h < 2; ++h) {
        const int off = (h * 32 + g * 8) ^ sw;
        aqh[h] = *(const bf16x8*)(qh_s + abase + off);
        aql[h] = *(const bf16x8*)(ql_s + abase + off);
      }
      f32x4 acc = {0.f, 0.f, 0.f, 0.f};
#pragma unroll
      for (int h = 0; h < 2; ++h) {         // IDENTICAL order in pass 2
        acc = MFMA(aqh[h], kbh[h], acc);
        acc = MFMA(aql[h], kbh[h], acc);
        acc = MFMA(aqh[h], kbl[h], acc);
      }
      float s[4];
#pragma unroll
      for (int r = 0; r < 4; ++r) {
        const int q = qt * 16 + g * 4 + r;
        const int midx = q * 64 + (colT ^ (((q >> 2) & 3) << 4));
        s[r] = mk_s[midx] ? MASKED : acc[r];
      }
      float lm = fmaxf(fmaxf(s[0], s[1]), fmaxf(s[2], s[3]));
      float nm = fmaxf(m_r, lm);
      l_r = l_r * exp2f(m_r - nm)
          + exp2f(s[0] - nm) + exp2f(s[1] - nm)
          + exp2f(s[2] - nm) + exp2f(s[3] - nm);
      m_r = nm;
    }
  }

  // lanes c, c+16, c+32, c+48 hold the same column: butterfly combine
#pragma unroll
  for (int off = 16; off <= 32; off <<= 1) {
    float mo = __shfl_xor(m_r, off, 64);
    float lo = __shfl_xor(l_r, off, 64);
    float nm = fmaxf(m_r, mo);
    l_r = l_r * exp2f(m_r - nm) + lo * exp2f(mo - nm);
    m_r = nm;
  }
  if (g == 0) {
    const int col = kc * 64 + w * 16 + c;
    m2_out[(size_t)bh * S_LEN + col] = m_r;
    il_out[(size_t)bh * S_LEN + col] = 1.0f / l_r;
  }
}

// ---------------------------------------------------------------------------
// Pass 2: out[q,d] = sum_k exp2(s2[q,k]-m2[k])*il[k] * v[k,d]
// Block = (qc 64 q-rows, bh); wave w owns q rows 16w..16w+16 (Q frags in
// regs); streams k in 64 chunks; K hi/lo + V^T(bf16) + mask staged in LDS;
// P round-trips through per-wave LDS tile into the PV MFMA.
// ---------------------------------------------------------------------------
__global__ __launch_bounds__(256) void pass2_out(
    const float* __restrict__ Q, const float* __restrict__ K,
    const float* __restrict__ V, const int* __restrict__ mask,
    const float* __restrict__ m2_in, const float* __restrict__ il_in,
    float* __restrict__ out) {
  __shared__ u16 kh_s[4096];
  __shared__ u16 kl_s[4096];
  __shared__ u16 vt_s[4096];
  __shared__ u16 p_s[4096];
  __shared__ int mk_s[4096];

  const int tid = threadIdx.x;
  const int lane = tid & 63;
  const int w = tid >> 6;
  const int c = lane & 15;
  const int g = lane >> 4;
  const int qc = blockIdx.x;
  const int bh = blockIdx.y;

  const float* Qb = Q + (size_t)bh * S_LEN * 64;
  const float* Kb = K + (size_t)bh * S_LEN * 64;
  const float* Vb = V + (size_t)bh * S_LEN * 64;

  // Q A-frags (scaled + split), held in registers for the whole block
  bf16x8 aqh[2], aql[2];
  {
    const int qrow = qc * 64 + w * 16 + c;
#pragma unroll
    for (int h = 0; h < 2; ++h) {
      const float* src = Qb + (size_t)qrow * 64 + h * 32 + g * 8;
      float4 x = *(const float4*)(src);
      float4 y = *(const float4*)(src + 4);
      float xs[8] = {x.x, x.y, x.z, x.w, y.x, y.y, y.z, y.w};
#pragma unroll
      for (int e = 0; e < 8; ++e) {
        u16 hh, ll; bfsplit(xs[e] * SC, hh, ll);
        aqh[h][e] = (short)hh; aql[h][e] = (short)ll;
      }
    }
  }

  f32x4 oacc[4];
#pragma unroll
  for (int dt = 0; dt < 4; ++dt) oacc[dt] = (f32x4){0.f, 0.f, 0.f, 0.f};

  const int slot = tid & 15, r0 = tid >> 4;
  const int kv = tid & 63, dblk = tid >> 6;

  for (int kc = 0; kc < NCH; ++kc) {
    __syncthreads();
    // stage K hi/lo + mask tile
#pragma unroll
    for (int p = 0; p < 4; ++p) {
      const int row = p * 16 + r0;
      float4 kvv = *(const float4*)(Kb + (size_t)(kc * 64 + row) * 64 + slot * 4);
      float xs[4] = {kvv.x, kvv.y, kvv.z, kvv.w};
      u16 ha[4], la[4];
#pragma unroll
      for (int e = 0; e < 4; ++e) bfsplit(xs[e], ha[e], la[e]);
      const int idx = row * 64 + ((slot * 4) ^ ((row & 7) << 3));
      *(ushort4*)(kh_s + idx) = make_ushort4(ha[0], ha[1], ha[2], ha[3]);
      *(ushort4*)(kl_s + idx) = make_ushort4(la[0], la[1], la[2], la[3]);
      int4 mv = *(const int4*)(mask + (size_t)(qc * 64 + row) * S_LEN + kc * 64 + slot * 4);
      const int midx = row * 64 + ((slot * 4) ^ (((row >> 2) & 3) << 4));
      *(int4*)(mk_s + midx) = mv;
    }
    // stage V transposed -> vt_s[d][k] bf16, swizzled (writes are 2-way free)
#pragma unroll
    for (int u = 0; u < 4; ++u) {
      float4 vv = *(const float4*)(Vb + (size_t)(kc * 64 + kv) * 64 + dblk * 16 + u * 4);
      float xs[4] = {vv.x, vv.y, vv.z, vv.w};
#pragma unroll
      for (int e = 0; e < 4; ++e) {
        const int d = dblk * 16 + u * 4 + e;
        vt_s[d * 64 + (kv ^ ((d & 7) << 3))] = f2bf_rne(xs[e]);
      }
    }
    __syncthreads();

    // scores -> P (per-wave LDS tile, bf16)
#pragma unroll
    for (int kt = 0; kt < 4; ++kt) {
      const int krow = kt * 16 + c;
      const int kbase = krow * 64, ksw = (krow & 7) << 3;
      bf16x8 bkh[2], bkl[2];
#pragma unroll
      for (int h = 0; h < 2; ++h) {
        const int off = (h * 32 + g * 8) ^ ksw;
        bkh[h] = *(const bf16x8*)(kh_s + kbase + off);
        bkl[h] = *(const bf16x8*)(kl_s + kbase + off);
      }
      f32x4 acc = {0.f, 0.f, 0.f, 0.f};
#pragma unroll
      for (int h = 0; h < 2; ++h) {         // IDENTICAL order to pass 1
        acc = MFMA(aqh[h], bkh[h], acc);
        acc = MFMA(aql[h], bkh[h], acc);
        acc = MFMA(aqh[h], bkl[h], acc);
      }
      const int gcol = kc * 64 + kt * 16 + c;
      const float m2c = m2_in[(size_t)bh * S_LEN + gcol];
      const float ilc = il_in[(size_t)bh * S_LEN + gcol];
#pragma unroll
      for (int r = 0; r < 4; ++r) {
        const int rowT = w * 16 + g * 4 + r;
        const int colT = kt * 16 + c;
        const int midx = rowT * 64 + (colT ^ (((rowT >> 2) & 3) << 4));
        const float s = mk_s[midx] ? MASKED : acc[r];
        const float p = exp2f(s - m2c) * ilc;
        const int qL = g * 4 + r;
        p_s[w * 1024 + qL * 64 + (colT ^ ((qL & 7) << 3))] = f2bf_rne(p);
      }
    }

    // PV: out[16q x 64d] += P[16q x 64k] * V[64k x 64d]
    bf16x8 pa[2];
    {
      const int pbase = w * 1024 + c * 64, psw = (c & 7) << 3;
#pragma unroll
      for (int h = 0; h < 2; ++h)
        pa[h] = *(const bf16x8*)(p_s + pbase + ((h * 32 + g * 8) ^ psw));
    }
#pragma unroll
    for (int dt = 0; dt < 4; ++dt) {
      const int drow = dt * 16 + c;
      const int vbase = drow * 64, vsw = (drow & 7) << 3;   // (dt*16+c)&7 == c&7
#pragma unroll
      for (int h = 0; h < 2; ++h) {
        bf16x8 bv = *(const bf16x8*)(vt_s + vbase + ((h * 32 + g * 8) ^ vsw));
        oacc[dt] = MFMA(pa[h], bv, oacc[dt]);
      }
    }
  }

  // epilogue: C-layout row = g*4+r, col = dt*16+c
  float* ob = out + ((size_t)bh * S_LEN + qc * 64 + w * 16) * 64;
#pragma unroll
  for (int dt = 0; dt < 4; ++dt)
#pragma unroll
    for (int r = 0; r < 4; ++r)
      ob[(size_t)(g * 4 + r) * 64 + dt * 16 + c] = oacc[dt][r];
}

extern "C" void kernel_launch(void* const* d_in, const int* in_sizes, int n_in,
                              void* d_out, int out_size, void* d_ws, size_t ws_size,
                              hipStream_t stream) {
  (void)in_sizes; (void)n_in; (void)out_size; (void)ws_size;
  const float* q = (const float*)d_in[0];
  const float* k = (const float*)d_in[1];
  const float* v = (const float*)d_in[2];
  const int* mask = (const int*)d_in[3];
  float* out = (float*)d_out;

  float* m2 = (float*)d_ws;                    // [32*2048]
  float* il = m2 + (size_t)N_BH * S_LEN;       // [32*2048]

  dim3 grid(NCH, N_BH);
  pass1_colstats<<<grid, 256, 0, stream>>>(q, k, mask, m2, il);
  pass2_out<<<grid, 256, 0, stream>>>(q, k, v, mask, m2, il, out);
}